// Round 6
// baseline (258.367 us; speedup 1.0000x reference)
//
#include <hip/hip_runtime.h>
#include <cstdint>
#include <cstddef>

// ---------------------------------------------------------------------------
// MultiHeadAttention forward, MI355X/gfx950.
// cvt(fp32->bf16) -> fused QKV GEMM (MFMA) -> flash attention -> out-proj.
// MFMA layouts (m89/m91/m120):
//   K=32 A-frag: lane l holds A[m=l&15][k=(l>>4)*8+j], j=0..7
//   K=32 B-frag: lane l holds Bt[n=l&15][k=(l>>4)*8+j]
//   K=16 A/B-frag: lane l holds X[.=l&15][k=(l>>4)*4+c], c=0..3
//   C/D: lane l, reg r holds D[m=(l>>4)*4+r][n=l&15]
// R6:
//  * attn: in-block key-split (8 waves = 4 q-groups x 2 key-halves, q-tile 64,
//    grid 1024 blocks -> 4 blocks/CU, occupancy cap 100% vs R5's 50%).
//    Per-wave state SMALLER than R5 (s[4],pk[4]) -> no spills.
//  * exp2-domain softmax: Q projection pre-scaled by (1/sqrt(64))*log2(e);
//    attn uses raw v_exp_f32 (2^x) -> no scale muls in the hot loop.
//  * oproj: 64x64 tiles, grid 1024 blocks (was 256 = 1 block/CU).
// ---------------------------------------------------------------------------

#define D_MODEL 1024
#define NHEAD   16
#define HDIM    64
#define BATCH   2
#define SEQ     2048
#define BT      (BATCH * SEQ)   // 4096

// (1/sqrt(HDIM)) * log2(e) -- folds softmax scale + exp->exp2 conversion
#define QSCALE 0.18033688011112043f

typedef __bf16 bf16;
typedef __bf16 bf16x8 __attribute__((ext_vector_type(8)));
typedef __bf16 bf16x4 __attribute__((ext_vector_type(4)));
typedef float  floatx4 __attribute__((ext_vector_type(4)));
typedef short  short4v __attribute__((ext_vector_type(4)));

#define MFMA16(a, b, c) __builtin_amdgcn_mfma_f32_16x16x32_bf16((a), (b), (c), 0, 0, 0)

__device__ __forceinline__ floatx4 MFMA16B(bf16x4 a, bf16x4 b, floatx4 c) {
  return __builtin_amdgcn_mfma_f32_16x16x16bf16_1k(
      __builtin_bit_cast(short4v, a), __builtin_bit_cast(short4v, b), c, 0, 0, 0);
}

__device__ __forceinline__ float fexp2(float x) {
  return __builtin_amdgcn_exp2f(x);   // v_exp_f32: D = 2^S0
}

// async global->LDS, 16B per lane. LDS dest = wave-uniform base + lane*16.
__device__ __forceinline__ void async_cp16(const bf16* g, bf16* l) {
  __builtin_amdgcn_global_load_lds(
      (__attribute__((address_space(1))) void*)(g),
      (__attribute__((address_space(3))) void*)(l), 16, 0, 0);
}

// ---------------------------------------------------------------------------
// fp32 -> bf16 conversion for q,k,v and the 4 weight matrices.
// ---------------------------------------------------------------------------
__global__ __launch_bounds__(256) void cvt7(
    const float* __restrict__ s0, const float* __restrict__ s1,
    const float* __restrict__ s2, const float* __restrict__ s3,
    const float* __restrict__ s4, const float* __restrict__ s5,
    const float* __restrict__ s6,
    bf16* __restrict__ d0, bf16* __restrict__ d1, bf16* __restrict__ d2,
    bf16* __restrict__ d3, bf16* __restrict__ d4, bf16* __restrict__ d5,
    bf16* __restrict__ d6)
{
  const float* src; bf16* dst; int n4;
  switch (blockIdx.y) {
    case 0:  src = s0; dst = d0; n4 = (BT * D_MODEL) / 4; break;
    case 1:  src = s1; dst = d1; n4 = (BT * D_MODEL) / 4; break;
    case 2:  src = s2; dst = d2; n4 = (BT * D_MODEL) / 4; break;
    case 3:  src = s3; dst = d3; n4 = (D_MODEL * D_MODEL) / 4; break;
    case 4:  src = s4; dst = d4; n4 = (D_MODEL * D_MODEL) / 4; break;
    case 5:  src = s5; dst = d5; n4 = (D_MODEL * D_MODEL) / 4; break;
    default: src = s6; dst = d6; n4 = (D_MODEL * D_MODEL) / 4; break;
  }
  int stride = gridDim.x * blockDim.x;
  for (int i = blockIdx.x * blockDim.x + threadIdx.x; i < n4; i += stride) {
    float4 f = ((const float4*)src)[i];
    bf16x4 h;
    h[0] = (bf16)f.x; h[1] = (bf16)f.y; h[2] = (bf16)f.z; h[3] = (bf16)f.w;
    ((bf16x4*)dst)[i] = h;
  }
}

// ---------------------------------------------------------------------------
// 128x128-tile GEMM core, K=1024, BK=32 (m97 structure).
// ---------------------------------------------------------------------------
__device__ __forceinline__ void gemm128_core(
    const bf16* __restrict__ A, const bf16* __restrict__ W,
    int m0, int n0, bf16* As, bf16* Bs, floatx4 acc[4][4])
{
  const int t = threadIdx.x;
  const int l = t & 63, w = t >> 6;
  const int quad = l >> 4, lr = l & 15;
  const int wm = (w >> 1) * 64, wn = (w & 1) * 64;

  floatx4 z = {0.f, 0.f, 0.f, 0.f};
#pragma unroll
  for (int i = 0; i < 4; i++)
#pragma unroll
    for (int j = 0; j < 4; j++) acc[i][j] = z;

  for (int kt = 0; kt < 1024; kt += 32) {
    __syncthreads();
#pragma unroll
    for (int i = 0; i < 2; i++) {
      int c = i * 256 + t;
      int row = c >> 2, ci = c & 3;
      async_cp16(A + (size_t)(m0 + row) * 1024 + kt + ci * 8,
                 As + (i * 256 + w * 64) * 8);
      async_cp16(W + (size_t)(n0 + row) * 1024 + kt + ci * 8,
                 Bs + (i * 256 + w * 64) * 8);
    }
    __syncthreads();

    bf16x8 af[4], bfr[4];
#pragma unroll
    for (int i = 0; i < 4; i++) {
      af[i]  = *(const bf16x8*)(As + (wm + i * 16 + lr) * 32 + quad * 8);
      bfr[i] = *(const bf16x8*)(Bs + (wn + i * 16 + lr) * 32 + quad * 8);
    }
#pragma unroll
    for (int i = 0; i < 4; i++)
#pragma unroll
      for (int j = 0; j < 4; j++)
        acc[i][j] = MFMA16(af[i], bfr[j], acc[i][j]);
  }
}

// ---------------------------------------------------------------------------
// Fused QKV projection. zid selects (q,Wq)->qh, (k,Wk)->kh, (v,Wv)->vt.
// qh,kh: [B*H][T][64]; v stored TRANSPOSED [B*H][64][T].
// qh is pre-scaled by QSCALE (softmax scale folded + exp2 domain).
// ---------------------------------------------------------------------------
__global__ __launch_bounds__(256) void qkv_gemm(
    const bf16* __restrict__ qb, const bf16* __restrict__ kb, const bf16* __restrict__ vb,
    const bf16* __restrict__ wq, const bf16* __restrict__ wk, const bf16* __restrict__ wv,
    const float* __restrict__ biasq, const float* __restrict__ biask, const float* __restrict__ biasv,
    bf16* __restrict__ qh, bf16* __restrict__ kh, bf16* __restrict__ vt)
{
  __shared__ bf16 As[128 * 32];
  __shared__ bf16 Bs[128 * 32];
  const int zid = blockIdx.z;
  const bf16* A = (zid == 0) ? qb : ((zid == 1) ? kb : vb);
  const bf16* W = (zid == 0) ? wq : ((zid == 1) ? wk : wv);
  const float* bias = (zid == 0) ? biasq : ((zid == 1) ? biask : biasv);
  const int m0 = blockIdx.x * 128, n0 = blockIdx.y * 128;

  floatx4 acc[4][4];
  gemm128_core(A, W, m0, n0, As, Bs, acc);

  const int t = threadIdx.x, l = t & 63, w = t >> 6;
  const int quad = l >> 4, lr = l & 15;
  const int wm = (w >> 1) * 64, wn = (w & 1) * 64;
  const float sc = (zid == 0) ? QSCALE : 1.0f;

  if (zid < 2) {
    bf16* out = (zid == 0) ? qh : kh;
#pragma unroll
    for (int i = 0; i < 4; i++) {
      int mbase = m0 + wm + i * 16 + quad * 4;       // global row (b*2048+t)
      int b  = mbase >> 11;
      int tq = mbase & 2047;
#pragma unroll
      for (int j = 0; j < 4; j++) {
        int n = n0 + wn + j * 16 + lr;               // e = h*64 + dh
        float bv = bias[n];
        int h = n >> 6, dh = n & 63;
        bf16* p = out + ((size_t)((b * NHEAD + h) * SEQ + tq)) * HDIM + dh;
#pragma unroll
        for (int r = 0; r < 4; r++)
          p[(size_t)r * HDIM] = (bf16)((acc[i][j][r] + bv) * sc);
      }
    }
  } else {
#pragma unroll
    for (int i = 0; i < 4; i++) {
      int mbase = m0 + wm + i * 16 + quad * 4;
      int b  = mbase >> 11;
      int tq = mbase & 2047;
#pragma unroll
      for (int j = 0; j < 4; j++) {
        int n = n0 + wn + j * 16 + lr;
        float bv = bias[n];
        int h = n >> 6, dh = n & 63;
        bf16x4 pk;
#pragma unroll
        for (int r = 0; r < 4; r++) pk[r] = (bf16)(acc[i][j][r] + bv);
        *(bf16x4*)(vt + ((size_t)((b * NHEAD + h) * HDIM + dh)) * SEQ + tq) = pk;
      }
    }
  }
}

// ---------------------------------------------------------------------------
// Flash attention, in-block key-split. Grid (T/64, B*H), block 512 = 8 waves:
// wave w -> q-group qg = w&3 (16 q-rows), key-half = w>>2 (64 keys/tile).
// Per 128-key tile: S^T = MFMA16x16x32(K,Q) (lane q = lr), per-lane exp2
// softmax, in-register PV via MFMA16x16x16 (C-layout == K=16 B-layout).
// Epilogue: merge the two key-half states per q-group via LDS overlay,
// normalize, coalesced 16B store.
// ---------------------------------------------------------------------------
__global__ __launch_bounds__(512, 6) void attn_fused(
    const bf16* __restrict__ qh, const bf16* __restrict__ kh,
    const bf16* __restrict__ vt, bf16* __restrict__ attn)
{
  __shared__ __align__(16) char smem[35840];
  bf16* Ks  = (bf16*)smem;            // [128][72], 18432 B
  bf16* Vts = (bf16*)(smem + 18432);  // [64][136], 17408 B
  // epilogue overlay: O-tiles @0 (16*1024B), stats @16384 (512B), Ost @16896

  const int t = threadIdx.x, l = t & 63, w = t >> 6;   // w in 0..7
  const int quad = l >> 4, lr = l & 15;
  const int qg = w & 3, half = w >> 2;
  const int bh = blockIdx.y;
  const int qt0 = blockIdx.x * 64;
  const bf16* qg_ = qh + (size_t)bh * SEQ * HDIM;
  const bf16* kg  = kh + (size_t)bh * SEQ * HDIM;
  const bf16* vg  = vt + (size_t)bh * HDIM * SEQ;

  // Q B-frags (K=32) for this wave's 16 q-rows: q = qt0 + qg*16 + lr.
  bf16x8 qf[2];
#pragma unroll
  for (int ko = 0; ko < 2; ko++)
    qf[ko] = *(const bf16x8*)(qg_ + (size_t)(qt0 + qg * 16 + lr) * HDIM
                              + ko * 32 + quad * 8);

  floatx4 zz = {0.f, 0.f, 0.f, 0.f};
  floatx4 Oacc[4];   // O^T[d = dt*16 + quad*4 + r][q = lr]
#pragma unroll
  for (int dt = 0; dt < 4; dt++) Oacc[dt] = zz;
  float mrow = -3.0e38f, lrow = 0.f;

  for (int kt0 = 0; kt0 < SEQ; kt0 += 128) {
    __syncthreads();
    // Stage K-tile [128][64] and V^T-tile [64][128], 16B chunks, 512 threads.
#pragma unroll
    for (int i = 0; i < 2; i++) {
      int c = t + 512 * i;
      { int row = c >> 3, ci = c & 7;   // K: 8 chunks/row
        *(int4*)(Ks + row * 72 + ci * 8) =
            *(const int4*)(kg + (size_t)(kt0 + row) * HDIM + ci * 8); }
      { int row = c >> 4, ci = c & 15;  // V^T: 16 chunks/row
        *(int4*)(Vts + row * 136 + ci * 8) =
            *(const int4*)(vg + (size_t)row * SEQ + kt0 + ci * 8); }
    }
    __syncthreads();

    // S^T over this wave's 64 keys: lane holds
    // S[q=lr][key = half*64 + ni*16 + quad*4 + r], ni=0..3. (exp2 domain)
    floatx4 s[4];
#pragma unroll
    for (int ni = 0; ni < 4; ni++) {
      const bf16* krow = Ks + (half * 64 + ni * 16 + lr) * 72 + quad * 8;
      bf16x8 k0 = *(const bf16x8*)(krow);
      bf16x8 k1 = *(const bf16x8*)(krow + 32);
      floatx4 a = zz;
      a = MFMA16(k0, qf[0], a);
      a = MFMA16(k1, qf[1], a);
      s[ni] = a;
    }

    // Per-lane online softmax (q = lr; reduce over the 4 quad-lanes).
    float rmax = s[0][0];
#pragma unroll
    for (int ni = 0; ni < 4; ni++)
#pragma unroll
      for (int r = 0; r < 4; r++) rmax = fmaxf(rmax, s[ni][r]);
    rmax = fmaxf(rmax, __shfl_xor(rmax, 16, 64));
    rmax = fmaxf(rmax, __shfl_xor(rmax, 32, 64));
    float mnew = fmaxf(mrow, rmax);
    float al = fexp2(mrow - mnew);
    mrow = mnew;

    bf16x4 pk[4];
    float rsum = 0.f;
#pragma unroll
    for (int ni = 0; ni < 4; ni++)
#pragma unroll
      for (int r = 0; r < 4; r++) {
        float pv = fexp2(s[ni][r] - mnew);
        rsum += pv;
        pk[ni][r] = (bf16)pv;
      }
    rsum += __shfl_xor(rsum, 16, 64);
    rsum += __shfl_xor(rsum, 32, 64);
    lrow = lrow * al + rsum;
#pragma unroll
    for (int dt = 0; dt < 4; dt++)
#pragma unroll
      for (int r = 0; r < 4; r++) Oacc[dt][r] *= al;

    // PV: O^T += MFMA_16x16x16(Vt_frag, P_frag); P in regs (pk).
#pragma unroll
    for (int ni = 0; ni < 4; ni++)
#pragma unroll
      for (int dt = 0; dt < 4; dt++) {
        bf16x4 vf = *(const bf16x4*)(Vts + (dt * 16 + lr) * 136
                                     + half * 64 + ni * 16 + quad * 4);
        Oacc[dt] = MFMA16B(vf, pk[ni], Oacc[dt]);
      }
  }

  // ---- Epilogue: merge key-half states, normalize, coalesced store. ----
  __syncthreads();   // done with Ks/Vts; overlay below
  bf16* Ost = (bf16*)(smem + 16896);  // [64][72]

  if (half == 1) {
#pragma unroll
    for (int dt = 0; dt < 4; dt++)
      *(floatx4*)(smem + (qg * 4 + dt) * 1024 + l * 16) = Oacc[dt];
    if (quad == 0)
      *(float2*)(smem + 16384 + (qg * 16 + lr) * 8) = make_float2(mrow, lrow);
  }
  __syncthreads();

  if (half == 0) {
    float2 st = *(const float2*)(smem + 16384 + (qg * 16 + lr) * 8);
    float ms = fmaxf(mrow, st.x);
    float fA = fexp2(mrow - ms);
    float fB = fexp2(st.x - ms);
    float inv = 1.0f / (lrow * fA + st.y * fB);
    float gA = fA * inv, gB = fB * inv;
#pragma unroll
    for (int dt = 0; dt < 4; dt++) {
      floatx4 ob = *(const floatx4*)(smem + (qg * 4 + dt) * 1024 + l * 16);
      bf16x4 ov;
#pragma unroll
      for (int r = 0; r < 4; r++)
        ov[r] = (bf16)(Oacc[dt][r] * gA + ob[r] * gB);
      *(bf16x4*)(Ost + (size_t)(qg * 16 + lr) * 72 + dt * 16 + quad * 4) = ov;
    }
  }
  __syncthreads();

  // stream Ost [64 q][64 d] to attn[b][qt0+row][h*64 + d], 1 int4/thread.
  const int b = bh >> 4, h = bh & 15;
  {
    int row = t >> 3, ci = t & 7;
    *(int4*)(attn + ((size_t)b * SEQ + qt0 + row) * D_MODEL + h * HDIM + ci * 8) =
        *(const int4*)(Ost + row * 72 + ci * 8);
  }
}

// ---------------------------------------------------------------------------
// Output projection: out = attn @ Wo^T + bo, fp32 output.
// 64x64 tiles -> grid 1024 blocks (4 blocks/CU; old 128x128 gave 1/CU).
// ---------------------------------------------------------------------------
__global__ __launch_bounds__(256) void oproj_gemm(
    const bf16* __restrict__ attn, const bf16* __restrict__ wo,
    const float* __restrict__ bo, float* __restrict__ out)
{
  __shared__ bf16 As[64 * 32];
  __shared__ bf16 Bs[64 * 32];
  const int m0 = blockIdx.x * 64, n0 = blockIdx.y * 64;
  const int t = threadIdx.x, l = t & 63, w = t >> 6;
  const int quad = l >> 4, lr = l & 15;
  const int wm = (w >> 1) * 32, wn = (w & 1) * 32;

  floatx4 z = {0.f, 0.f, 0.f, 0.f};
  floatx4 acc[2][2];
#pragma unroll
  for (int i = 0; i < 2; i++)
#pragma unroll
    for (int j = 0; j < 2; j++) acc[i][j] = z;

  for (int kt = 0; kt < 1024; kt += 32) {
    __syncthreads();
    {
      int row = t >> 2, ci = t & 3;   // 256 chunks each for A and B
      async_cp16(attn + (size_t)(m0 + row) * 1024 + kt + ci * 8,
                 As + (w * 64) * 8);
      async_cp16(wo + (size_t)(n0 + row) * 1024 + kt + ci * 8,
                 Bs + (w * 64) * 8);
    }
    __syncthreads();

    bf16x8 af[2], bfr[2];
#pragma unroll
    for (int i = 0; i < 2; i++) {
      af[i]  = *(const bf16x8*)(As + (wm + i * 16 + lr) * 32 + quad * 8);
      bfr[i] = *(const bf16x8*)(Bs + (wn + i * 16 + lr) * 32 + quad * 8);
    }
#pragma unroll
    for (int i = 0; i < 2; i++)
#pragma unroll
      for (int j = 0; j < 2; j++)
        acc[i][j] = MFMA16(af[i], bfr[j], acc[i][j]);
  }

#pragma unroll
  for (int i = 0; i < 2; i++) {
    int m = m0 + wm + i * 16 + quad * 4;
#pragma unroll
    for (int j = 0; j < 2; j++) {
      int n = n0 + wn + j * 16 + lr;
      float bv = bo[n];
      float* p = out + (size_t)m * D_MODEL + n;
#pragma unroll
      for (int r = 0; r < 4; r++)
        p[(size_t)r * D_MODEL] = acc[i][j][r] + bv;
    }
  }
}

// ---------------------------------------------------------------------------
extern "C" void kernel_launch(void* const* d_in, const int* in_sizes, int n_in,
                              void* d_out, int out_size, void* d_ws, size_t ws_size,
                              hipStream_t stream)
{
  const float* q  = (const float*)d_in[0];
  const float* k  = (const float*)d_in[1];
  const float* v  = (const float*)d_in[2];
  const float* Wq = (const float*)d_in[3];
  const float* bq = (const float*)d_in[4];
  const float* Wk = (const float*)d_in[5];
  const float* bk = (const float*)d_in[6];
  const float* Wv = (const float*)d_in[7];
  const float* bv = (const float*)d_in[8];
  const float* Wo = (const float*)d_in[9];
  const float* bo = (const float*)d_in[10];

  const size_t NQ = (size_t)BT * D_MODEL;        // 4194304
  const size_t NW = (size_t)D_MODEL * D_MODEL;   // 1048576

  bf16* p = (bf16*)d_ws;
  bf16* qb   = p; p += NQ;
  bf16* kb   = p; p += NQ;
  bf16* vb   = p; p += NQ;
  bf16* wqb  = p; p += NW;
  bf16* wkb  = p; p += NW;
  bf16* wvb  = p; p += NW;
  bf16* wob  = p; p += NW;
  bf16* qhp  = p; p += NQ;   // [B*H][T][64], pre-scaled by QSCALE
  bf16* khp  = p; p += NQ;   // [B*H][T][64]
  bf16* vtp  = p; p += NQ;   // [B*H][64][T]
  bf16* attn = p; p += NQ;   // [B][T][1024]

  cvt7<<<dim3(1024, 7, 1), 256, 0, stream>>>(q, k, v, Wq, Wk, Wv, Wo,
                                             qb, kb, vb, wqb, wkb, wvb, wob);
  qkv_gemm<<<dim3(32, 8, 3), 256, 0, stream>>>(qb, kb, vb, wqb, wkb, wvb,
                                               bq, bk, bv, qhp, khp, vtp);
  attn_fused<<<dim3(32, 32, 1), 512, 0, stream>>>(qhp, khp, vtp, attn);
  oproj_gemm<<<dim3(64, 16, 1), 256, 0, stream>>>(attn, wob, bo, (float*)d_out);
}

// Round 7
// 226.499 us; speedup vs baseline: 1.1407x; 1.1407x over previous
//
#include <hip/hip_runtime.h>
#include <cstdint>
#include <cstddef>

// ---------------------------------------------------------------------------
// MultiHeadAttention forward, MI355X/gfx950.
// cvt(fp32->bf16) -> fused QKV GEMM (MFMA) -> flash attention -> out-proj.
// MFMA layouts (m89/m91/m120):
//   K=32 A-frag: lane l holds A[m=l&15][k=(l>>4)*8+j], j=0..7
//   K=32 B-frag: lane l holds Bt[n=l&15][k=(l>>4)*8+j]
//   K=16 A/B-frag: lane l holds X[.=l&15][k=(l>>4)*4+c], c=0..3
//   C/D: lane l, reg r holds D[m=(l>>4)*4+r][n=l&15]
// R7: attn reverted to R5 wave shape (8 waves x 16 q-rows, all 128 keys,
// q-tile 128 -> grid 512 blocks) -- R6's key-split doubled staging per MAC
// and regressed. New staging:
//  * XOR-swizzled unpadded K/V LDS (K: chunk ci at ci^(row&7), stride 64 el;
//    V^T: chunk ci at ci^(row&15), stride 128 el) -> conflict-free frag reads
//    AND global_load_lds-compatible (no padding).
//  * global_load_lds (async DMA) staging: 4 x 1KB segments per wave per tile,
//    no VGPR round-trip, no staging address VALU.
//  * Double-buffered tiles, ONE barrier per tile (issue-after-barrier; DMA
//    lands during the ~1500-cyc compute phase).
// Kept from R6: exp2-domain softmax (QSCALE folded into Q projection),
// oproj 64x64 tiles.
// ---------------------------------------------------------------------------

#define D_MODEL 1024
#define NHEAD   16
#define HDIM    64
#define BATCH   2
#define SEQ     2048
#define BT      (BATCH * SEQ)   // 4096

// (1/sqrt(HDIM)) * log2(e) -- folds softmax scale + exp->exp2 conversion
#define QSCALE 0.18033688011112043f

typedef __bf16 bf16;
typedef __bf16 bf16x8 __attribute__((ext_vector_type(8)));
typedef __bf16 bf16x4 __attribute__((ext_vector_type(4)));
typedef float  floatx4 __attribute__((ext_vector_type(4)));
typedef short  short4v __attribute__((ext_vector_type(4)));

#define MFMA16(a, b, c) __builtin_amdgcn_mfma_f32_16x16x32_bf16((a), (b), (c), 0, 0, 0)

__device__ __forceinline__ floatx4 MFMA16B(bf16x4 a, bf16x4 b, floatx4 c) {
  return __builtin_amdgcn_mfma_f32_16x16x16bf16_1k(
      __builtin_bit_cast(short4v, a), __builtin_bit_cast(short4v, b), c, 0, 0, 0);
}

__device__ __forceinline__ float fexp2(float x) {
  return __builtin_amdgcn_exp2f(x);   // v_exp_f32: D = 2^S0
}

// async global->LDS, 16B per lane. LDS dest = wave-uniform base + lane*16.
__device__ __forceinline__ void async_cp16(const bf16* g, bf16* l) {
  __builtin_amdgcn_global_load_lds(
      (__attribute__((address_space(1))) void*)(g),
      (__attribute__((address_space(3))) void*)(l), 16, 0, 0);
}

// ---------------------------------------------------------------------------
// fp32 -> bf16 conversion for q,k,v and the 4 weight matrices.
// ---------------------------------------------------------------------------
__global__ __launch_bounds__(256) void cvt7(
    const float* __restrict__ s0, const float* __restrict__ s1,
    const float* __restrict__ s2, const float* __restrict__ s3,
    const float* __restrict__ s4, const float* __restrict__ s5,
    const float* __restrict__ s6,
    bf16* __restrict__ d0, bf16* __restrict__ d1, bf16* __restrict__ d2,
    bf16* __restrict__ d3, bf16* __restrict__ d4, bf16* __restrict__ d5,
    bf16* __restrict__ d6)
{
  const float* src; bf16* dst; int n4;
  switch (blockIdx.y) {
    case 0:  src = s0; dst = d0; n4 = (BT * D_MODEL) / 4; break;
    case 1:  src = s1; dst = d1; n4 = (BT * D_MODEL) / 4; break;
    case 2:  src = s2; dst = d2; n4 = (BT * D_MODEL) / 4; break;
    case 3:  src = s3; dst = d3; n4 = (D_MODEL * D_MODEL) / 4; break;
    case 4:  src = s4; dst = d4; n4 = (D_MODEL * D_MODEL) / 4; break;
    case 5:  src = s5; dst = d5; n4 = (D_MODEL * D_MODEL) / 4; break;
    default: src = s6; dst = d6; n4 = (D_MODEL * D_MODEL) / 4; break;
  }
  int stride = gridDim.x * blockDim.x;
  for (int i = blockIdx.x * blockDim.x + threadIdx.x; i < n4; i += stride) {
    float4 f = ((const float4*)src)[i];
    bf16x4 h;
    h[0] = (bf16)f.x; h[1] = (bf16)f.y; h[2] = (bf16)f.z; h[3] = (bf16)f.w;
    ((bf16x4*)dst)[i] = h;
  }
}

// ---------------------------------------------------------------------------
// 128x128-tile GEMM core, K=1024, BK=32 (m97 structure).
// ---------------------------------------------------------------------------
__device__ __forceinline__ void gemm128_core(
    const bf16* __restrict__ A, const bf16* __restrict__ W,
    int m0, int n0, bf16* As, bf16* Bs, floatx4 acc[4][4])
{
  const int t = threadIdx.x;
  const int l = t & 63, w = t >> 6;
  const int quad = l >> 4, lr = l & 15;
  const int wm = (w >> 1) * 64, wn = (w & 1) * 64;

  floatx4 z = {0.f, 0.f, 0.f, 0.f};
#pragma unroll
  for (int i = 0; i < 4; i++)
#pragma unroll
    for (int j = 0; j < 4; j++) acc[i][j] = z;

  for (int kt = 0; kt < 1024; kt += 32) {
    __syncthreads();
#pragma unroll
    for (int i = 0; i < 2; i++) {
      int c = i * 256 + t;
      int row = c >> 2, ci = c & 3;
      async_cp16(A + (size_t)(m0 + row) * 1024 + kt + ci * 8,
                 As + (i * 256 + w * 64) * 8);
      async_cp16(W + (size_t)(n0 + row) * 1024 + kt + ci * 8,
                 Bs + (i * 256 + w * 64) * 8);
    }
    __syncthreads();

    bf16x8 af[4], bfr[4];
#pragma unroll
    for (int i = 0; i < 4; i++) {
      af[i]  = *(const bf16x8*)(As + (wm + i * 16 + lr) * 32 + quad * 8);
      bfr[i] = *(const bf16x8*)(Bs + (wn + i * 16 + lr) * 32 + quad * 8);
    }
#pragma unroll
    for (int i = 0; i < 4; i++)
#pragma unroll
      for (int j = 0; j < 4; j++)
        acc[i][j] = MFMA16(af[i], bfr[j], acc[i][j]);
  }
}

// ---------------------------------------------------------------------------
// Fused QKV projection. zid selects (q,Wq)->qh, (k,Wk)->kh, (v,Wv)->vt.
// qh,kh: [B*H][T][64]; v stored TRANSPOSED [B*H][64][T].
// qh is pre-scaled by QSCALE (softmax scale folded + exp2 domain).
// ---------------------------------------------------------------------------
__global__ __launch_bounds__(256) void qkv_gemm(
    const bf16* __restrict__ qb, const bf16* __restrict__ kb, const bf16* __restrict__ vb,
    const bf16* __restrict__ wq, const bf16* __restrict__ wk, const bf16* __restrict__ wv,
    const float* __restrict__ biasq, const float* __restrict__ biask, const float* __restrict__ biasv,
    bf16* __restrict__ qh, bf16* __restrict__ kh, bf16* __restrict__ vt)
{
  __shared__ bf16 As[128 * 32];
  __shared__ bf16 Bs[128 * 32];
  const int zid = blockIdx.z;
  const bf16* A = (zid == 0) ? qb : ((zid == 1) ? kb : vb);
  const bf16* W = (zid == 0) ? wq : ((zid == 1) ? wk : wv);
  const float* bias = (zid == 0) ? biasq : ((zid == 1) ? biask : biasv);
  const int m0 = blockIdx.x * 128, n0 = blockIdx.y * 128;

  floatx4 acc[4][4];
  gemm128_core(A, W, m0, n0, As, Bs, acc);

  const int t = threadIdx.x, l = t & 63, w = t >> 6;
  const int quad = l >> 4, lr = l & 15;
  const int wm = (w >> 1) * 64, wn = (w & 1) * 64;
  const float sc = (zid == 0) ? QSCALE : 1.0f;

  if (zid < 2) {
    bf16* out = (zid == 0) ? qh : kh;
#pragma unroll
    for (int i = 0; i < 4; i++) {
      int mbase = m0 + wm + i * 16 + quad * 4;       // global row (b*2048+t)
      int b  = mbase >> 11;
      int tq = mbase & 2047;
#pragma unroll
      for (int j = 0; j < 4; j++) {
        int n = n0 + wn + j * 16 + lr;               // e = h*64 + dh
        float bv = bias[n];
        int h = n >> 6, dh = n & 63;
        bf16* p = out + ((size_t)((b * NHEAD + h) * SEQ + tq)) * HDIM + dh;
#pragma unroll
        for (int r = 0; r < 4; r++)
          p[(size_t)r * HDIM] = (bf16)((acc[i][j][r] + bv) * sc);
      }
    }
  } else {
#pragma unroll
    for (int i = 0; i < 4; i++) {
      int mbase = m0 + wm + i * 16 + quad * 4;
      int b  = mbase >> 11;
      int tq = mbase & 2047;
#pragma unroll
      for (int j = 0; j < 4; j++) {
        int n = n0 + wn + j * 16 + lr;
        float bv = bias[n];
        int h = n >> 6, dh = n & 63;
        bf16x4 pk;
#pragma unroll
        for (int r = 0; r < 4; r++) pk[r] = (bf16)(acc[i][j][r] + bv);
        *(bf16x4*)(vt + ((size_t)((b * NHEAD + h) * HDIM + dh)) * SEQ + tq) = pk;
      }
    }
  }
}

// ---------------------------------------------------------------------------
// Flash attention. Grid (T/128, B*H), block 512 = 8 waves; wave w owns
// q-rows qt0 + w*16 + lr, all 128 keys of each tile.
// LDS (double-buffered, 2 x 32 KB):
//   K  [128 rows][64 el],  8-el chunk ci stored at physical ci ^ (row & 7)
//   V^T[ 64 rows][128 el], 8-el chunk ci stored at physical ci ^ (row & 15)
// Staged via global_load_lds: 8 waves x (2 K-seg + 2 V-seg) x 1 KB per tile;
// lane l of segment s loads the global chunk destined for LDS slot s*64+l.
// One barrier per tile (issue DMA for tile k+1 right after barrier k).
// Compute: S^T = MFMA16x16x32(K,Q) (lane q = lr), per-lane exp2 softmax,
// in-register PV via MFMA16x16x16. Epilogue: normalize, LDS transpose,
// coalesced store.
// ---------------------------------------------------------------------------
__global__ __launch_bounds__(512, 4) void attn_fused(
    const bf16* __restrict__ qh, const bf16* __restrict__ kh,
    const bf16* __restrict__ vt, bf16* __restrict__ attn)
{
  __shared__ __align__(16) char smem[65536];   // 2 x (K 16KB + V 16KB)

  const int t = threadIdx.x, l = t & 63, w = t >> 6;   // w in 0..7
  const int quad = l >> 4, lr = l & 15;
  const int bh = blockIdx.y;
  const int qt0 = blockIdx.x * 128;
  const bf16* qg = qh + (size_t)bh * SEQ * HDIM;
  const bf16* kg = kh + (size_t)bh * SEQ * HDIM;
  const bf16* vg = vt + (size_t)bh * HDIM * SEQ;

  // Staging geometry (per wave, per tile): segments sA = w*2, sB = w*2+1.
  // K seg s: rows s*8+(l>>3), phys chunk l&7 <- global chunk (l&7)^(row&7).
  // V seg s: rows s*4+(l>>4), phys chunk l&15 <- global chunk (l&15)^(row&15).
  int krow0 = (w * 2) * 8 + (l >> 3);
  int krow1 = (w * 2 + 1) * 8 + (l >> 3);
  int kcl0  = (l & 7) ^ (krow0 & 7);
  int kcl1  = (l & 7) ^ (krow1 & 7);
  int vrow0 = (w * 2) * 4 + (l >> 4);
  int vrow1 = (w * 2 + 1) * 4 + (l >> 4);
  int vcl0  = (l & 15) ^ (vrow0 & 15);
  int vcl1  = (l & 15) ^ (vrow1 & 15);
  const bf16* kga = kg + (size_t)krow0 * HDIM + kcl0 * 8;
  const bf16* kgb = kg + (size_t)krow1 * HDIM + kcl1 * 8;
  const bf16* vga = vg + (size_t)vrow0 * SEQ + vcl0 * 8;
  const bf16* vgb = vg + (size_t)vrow1 * SEQ + vcl1 * 8;

  // Q B-frags (K=32) for this wave's 16 q-rows: q = qt0 + w*16 + lr.
  bf16x8 qf[2];
#pragma unroll
  for (int ko = 0; ko < 2; ko++)
    qf[ko] = *(const bf16x8*)(qg + (size_t)(qt0 + w * 16 + lr) * HDIM
                              + ko * 32 + quad * 8);

  floatx4 zz = {0.f, 0.f, 0.f, 0.f};
  floatx4 Oacc[4];   // O^T[d = dt*16 + quad*4 + r][q = lr]
#pragma unroll
  for (int dt = 0; dt < 4; dt++) Oacc[dt] = zz;
  float mrow = -3.0e38f, lrow = 0.f;

  // prologue: stage tile 0 into buffer 0
  {
    bf16* Kb = (bf16*)smem;
    bf16* Vb = (bf16*)(smem + 16384);
    async_cp16(kga, Kb + (w * 2) * 512);
    async_cp16(kgb, Kb + (w * 2 + 1) * 512);
    async_cp16(vga, Vb + (w * 2) * 512);
    async_cp16(vgb, Vb + (w * 2 + 1) * 512);
  }

  for (int kt = 0; kt < 16; kt++) {
    const int p = kt & 1;
    __syncthreads();   // drains vmcnt -> tile kt resident in buf p;
                       // all waves done reading buf 1-p (tile kt-1)
    if (kt + 1 < 16) {
      bf16* Kb = (bf16*)(smem + (1 - p) * 32768);
      bf16* Vb = (bf16*)(smem + (1 - p) * 32768 + 16384);
      int off = (kt + 1) * 128;
      async_cp16(kga + (size_t)off * HDIM, Kb + (w * 2) * 512);
      async_cp16(kgb + (size_t)off * HDIM, Kb + (w * 2 + 1) * 512);
      async_cp16(vga + off, Vb + (w * 2) * 512);
      async_cp16(vgb + off, Vb + (w * 2 + 1) * 512);
    }
    const bf16* Ks  = (const bf16*)(smem + p * 32768);
    const bf16* Vts = (const bf16*)(smem + p * 32768 + 16384);

    // S^T: lane holds S[q=lr][key = ni*16 + quad*4 + r], ni=0..7.
    floatx4 s[8];
#pragma unroll
    for (int ni = 0; ni < 8; ni++) {
      const bf16* krow = Ks + (ni * 16 + lr) * 64;
      bf16x8 k0 = *(const bf16x8*)(krow + ((quad ^ (lr & 7)) * 8));
      bf16x8 k1 = *(const bf16x8*)(krow + (((quad + 4) ^ (lr & 7)) * 8));
      floatx4 a = zz;
      a = MFMA16(k0, qf[0], a);
      a = MFMA16(k1, qf[1], a);
      s[ni] = a;
    }

    // Per-lane online softmax (q = lr; exp2 domain, scale pre-folded).
    float rmax = s[0][0];
#pragma unroll
    for (int ni = 0; ni < 8; ni++)
#pragma unroll
      for (int r = 0; r < 4; r++) rmax = fmaxf(rmax, s[ni][r]);
    rmax = fmaxf(rmax, __shfl_xor(rmax, 16, 64));
    rmax = fmaxf(rmax, __shfl_xor(rmax, 32, 64));
    float mnew = fmaxf(mrow, rmax);
    float al = fexp2(mrow - mnew);
    mrow = mnew;

    bf16x4 pk[8];
    float rsum = 0.f;
#pragma unroll
    for (int ni = 0; ni < 8; ni++)
#pragma unroll
      for (int r = 0; r < 4; r++) {
        float pv = fexp2(s[ni][r] - mnew);
        rsum += pv;
        pk[ni][r] = (bf16)pv;
      }
    rsum += __shfl_xor(rsum, 16, 64);
    rsum += __shfl_xor(rsum, 32, 64);
    lrow = lrow * al + rsum;
#pragma unroll
    for (int dt = 0; dt < 4; dt++)
#pragma unroll
      for (int r = 0; r < 4; r++) Oacc[dt][r] *= al;

    // PV: O^T += MFMA_16x16x16(Vt_frag, P_frag); P in regs (pk).
    // V logical key-offset ni*16+quad*4 -> chunk c=ni*2+(quad>>1), sub=(quad&1)*4;
    // physical chunk = c ^ (lr & 15)  (V row = dt*16+lr, row&15 == lr).
#pragma unroll
    for (int ni = 0; ni < 8; ni++)
#pragma unroll
      for (int dt = 0; dt < 4; dt++) {
        bf16x4 vf = *(const bf16x4*)(Vts + (dt * 16 + lr) * 128
                                     + (((ni * 2 + (quad >> 1)) ^ lr) * 8)
                                     + (quad & 1) * 4);
        Oacc[dt] = MFMA16B(vf, pk[ni], Oacc[dt]);
      }
  }

  // ---- Epilogue: normalize, transpose via LDS, coalesced store. ----
  // Buffer 0 was last read at tile 14; all waves are past the tile-15
  // barrier, so it is free for the Ost overlay ([128][72] padded).
  float inv = 1.0f / lrow;
  bf16* Ost = (bf16*)smem;
#pragma unroll
  for (int dt = 0; dt < 4; dt++) {
    bf16x4 ov;
#pragma unroll
    for (int r = 0; r < 4; r++) ov[r] = (bf16)(Oacc[dt][r] * inv);
    *(bf16x4*)(Ost + (size_t)(w * 16 + lr) * 72 + dt * 16 + quad * 4) = ov;
  }
  __syncthreads();

  // stream Ost [128 q][64 d] to attn[b][qt0+row][h*64 + d], coalesced 16B.
  const int b = bh >> 4, h = bh & 15;
#pragma unroll
  for (int i = 0; i < 2; i++) {
    int c = t + 512 * i;
    int row = c >> 3, ci = c & 7;
    *(int4*)(attn + ((size_t)b * SEQ + qt0 + row) * D_MODEL + h * HDIM + ci * 8) =
        *(const int4*)(Ost + row * 72 + ci * 8);
  }
}

// ---------------------------------------------------------------------------
// Output projection: out = attn @ Wo^T + bo, fp32 output.
// 64x64 tiles -> grid 1024 blocks (4 blocks/CU).
// ---------------------------------------------------------------------------
__global__ __launch_bounds__(256) void oproj_gemm(
    const bf16* __restrict__ attn, const bf16* __restrict__ wo,
    const float* __restrict__ bo, float* __restrict__ out)
{
  __shared__ bf16 As[64 * 32];
  __shared__ bf16 Bs[64 * 32];
  const int m0 = blockIdx.x * 64, n0 = blockIdx.y * 64;
  const int t = threadIdx.x, l = t & 63, w = t >> 6;
  const int quad = l >> 4, lr = l & 15;
  const int wm = (w >> 1) * 32, wn = (w & 1) * 32;

  floatx4 z = {0.f, 0.f, 0.f, 0.f};
  floatx4 acc[2][2];
#pragma unroll
  for (int i = 0; i < 2; i++)
#pragma unroll
    for (int j = 0; j < 2; j++) acc[i][j] = z;

  for (int kt = 0; kt < 1024; kt += 32) {
    __syncthreads();
    {
      int row = t >> 2, ci = t & 3;   // 256 chunks each for A and B
      async_cp16(attn + (size_t)(m0 + row) * 1024 + kt + ci * 8,
                 As + (w * 64) * 8);
      async_cp16(wo + (size_t)(n0 + row) * 1024 + kt + ci * 8,
                 Bs + (w * 64) * 8);
    }
    __syncthreads();

    bf16x8 af[2], bfr[2];
#pragma unroll
    for (int i = 0; i < 2; i++) {
      af[i]  = *(const bf16x8*)(As + (wm + i * 16 + lr) * 32 + quad * 8);
      bfr[i] = *(const bf16x8*)(Bs + (wn + i * 16 + lr) * 32 + quad * 8);
    }
#pragma unroll
    for (int i = 0; i < 2; i++)
#pragma unroll
      for (int j = 0; j < 2; j++)
        acc[i][j] = MFMA16(af[i], bfr[j], acc[i][j]);
  }

#pragma unroll
  for (int i = 0; i < 2; i++) {
    int m = m0 + wm + i * 16 + quad * 4;
#pragma unroll
    for (int j = 0; j < 2; j++) {
      int n = n0 + wn + j * 16 + lr;
      float bv = bo[n];
      float* p = out + (size_t)m * D_MODEL + n;
#pragma unroll
      for (int r = 0; r < 4; r++)
        p[(size_t)r * D_MODEL] = acc[i][j][r] + bv;
    }
  }
}

// ---------------------------------------------------------------------------
extern "C" void kernel_launch(void* const* d_in, const int* in_sizes, int n_in,
                              void* d_out, int out_size, void* d_ws, size_t ws_size,
                              hipStream_t stream)
{
  const float* q  = (const float*)d_in[0];
  const float* k  = (const float*)d_in[1];
  const float* v  = (const float*)d_in[2];
  const float* Wq = (const float*)d_in[3];
  const float* bq = (const float*)d_in[4];
  const float* Wk = (const float*)d_in[5];
  const float* bk = (const float*)d_in[6];
  const float* Wv = (const float*)d_in[7];
  const float* bv = (const float*)d_in[8];
  const float* Wo = (const float*)d_in[9];
  const float* bo = (const float*)d_in[10];

  const size_t NQ = (size_t)BT * D_MODEL;        // 4194304
  const size_t NW = (size_t)D_MODEL * D_MODEL;   // 1048576

  bf16* p = (bf16*)d_ws;
  bf16* qb   = p; p += NQ;
  bf16* kb   = p; p += NQ;
  bf16* vb   = p; p += NQ;
  bf16* wqb  = p; p += NW;
  bf16* wkb  = p; p += NW;
  bf16* wvb  = p; p += NW;
  bf16* wob  = p; p += NW;
  bf16* qhp  = p; p += NQ;   // [B*H][T][64], pre-scaled by QSCALE
  bf16* khp  = p; p += NQ;   // [B*H][T][64]
  bf16* vtp  = p; p += NQ;   // [B*H][64][T]
  bf16* attn = p; p += NQ;   // [B][T][1024]

  cvt7<<<dim3(1024, 7, 1), 256, 0, stream>>>(q, k, v, Wq, Wk, Wv, Wo,
                                             qb, kb, vb, wqb, wkb, wvb, wob);
  qkv_gemm<<<dim3(32, 8, 3), 256, 0, stream>>>(qb, kb, vb, wqb, wkb, wvb,
                                               bq, bk, bv, qhp, khp, vtp);
  attn_fused<<<dim3(16, 32, 1), 512, 0, stream>>>(qhp, khp, vtp, attn);
  oproj_gemm<<<dim3(64, 16, 1), 256, 0, stream>>>(attn, wob, bo, (float*)d_out);
}